// Round 6
// baseline (394.785 us; speedup 1.0000x reference)
//
#include <hip/hip_runtime.h>

typedef short bf16x8 __attribute__((ext_vector_type(8)));
typedef float f32x4 __attribute__((ext_vector_type(4)));

#define MFMA16(a,b,c) __builtin_amdgcn_mfma_f32_16x16x32_bf16((a),(b),(c),0,0,0)

static __device__ __forceinline__ unsigned short f2bf(float f){
  unsigned u; __builtin_memcpy(&u, &f, 4);
  u += 0x7fffu + ((u >> 16) & 1u);
  return (unsigned short)(u >> 16);
}
static __device__ __forceinline__ unsigned f32u(float f){
  unsigned u; __builtin_memcpy(&u, &f, 4); return u;
}

// ---------------------------------------------------------------------------
// Stage f32 tensor -> bf16.
// ---------------------------------------------------------------------------
__global__ __launch_bounds__(256) void cvt_bf16(
    const float* __restrict__ in, unsigned short* __restrict__ out, int n) {
  int i = blockIdx.x * 256 + threadIdx.x;
  if (i < n) out[i] = f2bf(in[i]);
}

// ---------------------------------------------------------------------------
// T0: x [n][512 c][1024 p] f32 -> xT [n][1024 p][512 c] bf16
// ---------------------------------------------------------------------------
__global__ __launch_bounds__(256) void transpose_cvt(
    const float* __restrict__ in, unsigned short* __restrict__ out)
{
  __shared__ unsigned short tile[32][33];
  const long base = (long)blockIdx.z * 512 * 1024;
  const int t = threadIdx.x, tx = t & 31, ty = t >> 5;
  const int c0 = blockIdx.x * 32, r0 = blockIdx.y * 32;
  const float* ib = in + base;
#pragma unroll
  for (int i = 0; i < 4; ++i)
    tile[ty + i * 8][tx] = f2bf(ib[(long)(r0 + ty + i * 8) * 1024 + c0 + tx]);
  __syncthreads();
  unsigned short* ob = out + base;
#pragma unroll
  for (int i = 0; i < 4; ++i)
    ob[(long)(c0 + ty + i * 8) * 512 + r0 + tx] = tile[tx][ty + i * 8];
}

// ---------------------------------------------------------------------------
// K1: QKV GEMM.  A = xT [n][1024 p][512 c] bf16, B = wq [1536 o][512 c] bf16,
// bias f32. Epilogue routes by o:
//   o in [0,512)    -> q_pd [n][h][p][64]  (qkv + 0)  PRE-SCALED by 0.125*log2e
//   o in [512,1024) -> k_pd [n][h][p][64]  (qkv + 8388608)
//   o in [1024,1536)-> v_cp [n][o-1024][p] (qkv + 16777216)
// ---------------------------------------------------------------------------
__global__ __launch_bounds__(256) void gemm_qkv(
    const unsigned short* __restrict__ A, const unsigned short* __restrict__ B,
    unsigned short* __restrict__ qkvout, const float* __restrict__ bias)
{
  const int M = 1024, K = 512;
  __shared__ unsigned short As[128 * 72];
  __shared__ unsigned short Bs[128 * 72];
  const int t = threadIdx.x, lane = t & 63, wv = t >> 6;
  const int quad = lane >> 4, ln = lane & 15;
  const int m0 = blockIdx.y * 128, n0 = blockIdx.x * 128;
  const long zb = blockIdx.z;
  A += zb * (long)M * K;

  f32x4 zero = {0.f, 0.f, 0.f, 0.f};
  f32x4 acc[4][4];
#pragma unroll
  for (int i = 0; i < 4; ++i)
#pragma unroll
    for (int j = 0; j < 4; ++j) acc[i][j] = zero;

  const int wm = (wv & 1) * 64, wn = (wv >> 1) * 64;

  for (int kt = 0; kt < K; kt += 64) {
#pragma unroll
    for (int i = 0; i < 4; ++i) {
      int chunk = t + 256 * i;
      int row = chunk >> 3, col = (chunk & 7) * 8;
      *(uint4*)&As[row * 72 + col] = *(const uint4*)&A[(long)(m0 + row) * K + kt + col];
      *(uint4*)&Bs[row * 72 + col] = *(const uint4*)&B[(long)(n0 + row) * K + kt + col];
    }
    __syncthreads();
#pragma unroll
    for (int kk = 0; kk < 64; kk += 32) {
      bf16x8 a[4], b[4];
#pragma unroll
      for (int i = 0; i < 4; ++i)
        a[i] = *(const bf16x8*)&As[(wm + i * 16 + ln) * 72 + kk + quad * 8];
#pragma unroll
      for (int j = 0; j < 4; ++j)
        b[j] = *(const bf16x8*)&Bs[(wn + j * 16 + ln) * 72 + kk + quad * 8];
#pragma unroll
      for (int i = 0; i < 4; ++i)
#pragma unroll
        for (int j = 0; j < 4; ++j)
          acc[i][j] = MFMA16(a[i], b[j], acc[i][j]);
    }
    __syncthreads();
  }

#pragma unroll
  for (int j = 0; j < 4; ++j) {
    int o = n0 + wn + j * 16 + ln;
    float bb = bias[o];
    int part = o >> 9;          // 0=q, 1=k, 2=v
    int h = (o >> 6) & 7, d = o & 63;
    float qs = (part == 0) ? 0.18033688f : 1.0f;  // 0.125 * log2(e)
#pragma unroll
    for (int i = 0; i < 4; ++i) {
      int p = m0 + wm + i * 16 + quad * 4;
      f32x4 v = acc[i][j];
      if (part < 2) {
        unsigned short* dst = qkvout + (long)part * 8388608
            + ((long)(zb * 8 + h) * 1024 + p) * 64 + d;
#pragma unroll
        for (int r = 0; r < 4; ++r) dst[r * 64] = f2bf((v[r] + bb) * qs);
      } else {
        long cidx = ((long)zb * 512 + (o - 1024)) * 1024 + p;
        ushort4 st;
        st.x = f2bf(v[0] + bb); st.y = f2bf(v[1] + bb);
        st.z = f2bf(v[2] + bb); st.w = f2bf(v[3] + bb);
        *(ushort4*)&qkvout[16777216 + cidx] = st;
      }
    }
  }
}

// ---------------------------------------------------------------------------
// K3: OUT GEMM + bias + dropout-scale + residual; f32 output.
// ---------------------------------------------------------------------------
__global__ __launch_bounds__(256) void gemm_out(
    const unsigned short* __restrict__ A, const unsigned short* __restrict__ B,
    float* __restrict__ C, const float* __restrict__ bias,
    const float* __restrict__ xin, const int* __restrict__ de_ptr)
{
  const int M = 1024, K = 512;
  __shared__ unsigned short As[128 * 72];
  __shared__ unsigned short Bs[128 * 72];
  const int t = threadIdx.x, lane = t & 63, wv = t >> 6;
  const int quad = lane >> 4, ln = lane & 15;
  const int m0 = blockIdx.y * 128, n0 = blockIdx.x * 128;
  const long zb = blockIdx.z;
  A += zb * (long)M * K;
  C += zb * 512l * M;
  xin += zb * 512l * M;

  f32x4 zero = {0.f, 0.f, 0.f, 0.f};
  f32x4 acc[4][4];
#pragma unroll
  for (int i = 0; i < 4; ++i)
#pragma unroll
    for (int j = 0; j < 4; ++j) acc[i][j] = zero;

  const int wm = (wv & 1) * 64, wn = (wv >> 1) * 64;

  for (int kt = 0; kt < K; kt += 64) {
#pragma unroll
    for (int i = 0; i < 4; ++i) {
      int chunk = t + 256 * i;
      int row = chunk >> 3, col = (chunk & 7) * 8;
      *(uint4*)&As[row * 72 + col] = *(const uint4*)&A[(long)(m0 + row) * K + kt + col];
      *(uint4*)&Bs[row * 72 + col] = *(const uint4*)&B[(long)(n0 + row) * K + kt + col];
    }
    __syncthreads();
#pragma unroll
    for (int kk = 0; kk < 64; kk += 32) {
      bf16x8 a[4], b[4];
#pragma unroll
      for (int i = 0; i < 4; ++i)
        a[i] = *(const bf16x8*)&As[(wm + i * 16 + ln) * 72 + kk + quad * 8];
#pragma unroll
      for (int j = 0; j < 4; ++j)
        b[j] = *(const bf16x8*)&Bs[(wn + j * 16 + ln) * 72 + kk + quad * 8];
#pragma unroll
      for (int i = 0; i < 4; ++i)
#pragma unroll
        for (int j = 0; j < 4; ++j)
          acc[i][j] = MFMA16(a[i], b[j], acc[i][j]);
    }
    __syncthreads();
  }

  float dscale = 1.0f / (1.0f - 0.1f * (float)de_ptr[0]);

#pragma unroll
  for (int j = 0; j < 4; ++j) {
    int o = n0 + wn + j * 16 + ln;
    float bb = bias[o];
#pragma unroll
    for (int i = 0; i < 4; ++i) {
      int p = m0 + wm + i * 16 + quad * 4;
      long cidx = (long)o * M + p;
      f32x4 v = acc[i][j];
      float4 rx = *(const float4*)&xin[cidx];
      float4 st;
      st.x = rx.x + (v[0] + bb) * dscale;
      st.y = rx.y + (v[1] + bb) * dscale;
      st.z = rx.z + (v[2] + bb) * dscale;
      st.w = rx.w + (v[3] + bb) * dscale;
      *(float4*)&C[cidx] = st;
    }
  }
}

// ---------------------------------------------------------------------------
// Flash attention v3 — BARRIER-FREE.
// grid (16 q-tiles, 128 (n,h)); 4 waves x 16 q-rows each.
// q_pd (pre-scaled by 0.125*log2e), k_pd: [(n*8+h)*1024 + p][64]
// v_cp: [n][c'=h*64+d][1024 p];  out y_pc: [n][1024 p][512 c'] bf16.
//
// K and V fragments are read DIRECTLY from global (A-operand layout, 16 B
// per lane; the block's 4 waves touch the same 16 KB tile near-simultaneously
// so L1 serves the redundancy). P goes through wave-private LDS (no barrier:
// same-wave ds ordering via lgkmcnt). Zero __syncthreads in the kernel —
// waves free-run; latency hidden by occupancy (LDS 17.4 KB, VGPR ~80).
// ---------------------------------------------------------------------------
__global__ __launch_bounds__(256) void attn_kernel(
    const unsigned short* __restrict__ q_pd, const unsigned short* __restrict__ k_pd,
    const unsigned short* __restrict__ v_cp, unsigned short* __restrict__ y_pc)
{
  __shared__ unsigned short Ps[4 * 16 * 136];    // 17.4 KB, per-wave private
  const int t = threadIdx.x, lane = t & 63, wv = t >> 6;
  const int quad = lane >> 4, ln = lane & 15;
  const int nh = blockIdx.y, n = nh >> 3, h = nh & 7;
  const int q0 = blockIdx.x * 64;

  // Q fragments (B-operand; n = ln, k = quad*8+j)
  bf16x8 qa[2];
  {
    const unsigned short* qb = q_pd + ((long)nh * 1024 + q0 + wv * 16 + ln) * 64;
    qa[0] = *(const bf16x8*)(qb + quad * 8);
    qa[1] = *(const bf16x8*)(qb + 32 + quad * 8);
  }

  f32x4 zero = {0.f, 0.f, 0.f, 0.f};
  float l_acc = 0.f;
  f32x4 o_acc[4];
#pragma unroll
  for (int nf = 0; nf < 4; ++nf) o_acc[nf] = zero;

  // lane-fixed pieces of the global K / V addresses
  const unsigned short* kb = k_pd + (long)nh * 1024 * 64
                           + (long)ln * 64 + quad * 8;     // + j*16*64 + c*128*64
  const unsigned short* vb = v_cp + ((long)n * 512 + h * 64) * 1024
                           + (long)ln * 1024 + quad * 8;   // + nf*16*1024 + c*128
  unsigned short* Pw = &Ps[wv * 16 * 136];

  for (int c = 0; c < 8; ++c) {
    const unsigned short* kg = kb + (long)c * 128 * 64;

    // ---- S^T = K Q^T : A = K frag straight from global ----
    f32x4 s[8];
#pragma unroll
    for (int j = 0; j < 8; ++j) {
      bf16x8 ka0 = *(const bf16x8*)(kg + j * 16 * 64);
      bf16x8 ka1 = *(const bf16x8*)(kg + j * 16 * 64 + 32);
      f32x4 sj = MFMA16(ka0, qa[0], zero);
      s[j] = MFMA16(ka1, qa[1], sj);
    }

    // ---- p = 2^s (logits pre-scaled; no max tracking needed) ----
    float ls = 0.f;
#pragma unroll
    for (int j = 0; j < 8; ++j) {
#pragma unroll
      for (int r = 0; r < 4; ++r) {
        float pv = __builtin_amdgcn_exp2f(s[j][r]);
        s[j][r] = pv;
        ls += pv;
      }
    }
    l_acc += ls;

    // ---- P[q=ln][key] -> wave-private LDS, packed b64 writes ----
#pragma unroll
    for (int j = 0; j < 8; ++j) {
      uint2 pk;
      pk.x = __builtin_amdgcn_perm(f32u(s[j][1]), f32u(s[j][0]), 0x07060302u);
      pk.y = __builtin_amdgcn_perm(f32u(s[j][3]), f32u(s[j][2]), 0x07060302u);
      *(uint2*)&Pw[ln * 136 + j * 16 + quad * 4] = pk;
    }

    // ---- O^T += V^T P^T : A = V frag straight from global, B = P frag ----
    bf16x8 ap[4];
#pragma unroll
    for (int k2 = 0; k2 < 4; ++k2)
      ap[k2] = *(const bf16x8*)&Pw[ln * 136 + k2 * 32 + quad * 8];
#pragma unroll
    for (int nf = 0; nf < 4; ++nf) {
#pragma unroll
      for (int k2 = 0; k2 < 4; ++k2) {
        bf16x8 va = *(const bf16x8*)(vb + (long)nf * 16 * 1024 + c * 128 + k2 * 32);
        o_acc[nf] = MFMA16(va, ap[k2], o_acc[nf]);
      }
    }
  }

  // reduce l across the 4 quads (thread's keys cover quad*4+{0..3} mod 16)
  l_acc += __shfl_xor(l_acc, 16);
  l_acc += __shfl_xor(l_acc, 32);
  float linv = 1.0f / l_acc;

  // O^T C-frag: row = d = nf*16 + quad*4 + r, col = q = ln -> packed b64 store
  const int p = q0 + wv * 16 + ln;
  unsigned short* yb = y_pc + ((long)n * 1024 + p) * 512 + h * 64 + quad * 4;
#pragma unroll
  for (int nf = 0; nf < 4; ++nf) {
    ushort4 st;
    st.x = f2bf(o_acc[nf][0] * linv);
    st.y = f2bf(o_acc[nf][1] * linv);
    st.z = f2bf(o_acc[nf][2] * linv);
    st.w = f2bf(o_acc[nf][3] * linv);
    *(ushort4*)&yb[nf * 16] = st;
  }
}

// ---------------------------------------------------------------------------
extern "C" void kernel_launch(void* const* d_in, const int* in_sizes, int n_in,
                              void* d_out, int out_size, void* d_ws, size_t ws_size,
                              hipStream_t stream) {
  (void)in_sizes; (void)n_in; (void)out_size; (void)ws_size;
  const float* x     = (const float*)d_in[0];
  const float* qkv_w = (const float*)d_in[1];
  const float* qkv_b = (const float*)d_in[2];
  const float* out_w = (const float*)d_in[3];
  const float* out_b = (const float*)d_in[4];
  const int* de = (const int*)d_in[5];
  float* out = (float*)d_out;
  unsigned short* ws = (unsigned short*)d_ws;

  // ws layout (shorts), ~66 MiB total:
  //   [0, 8388608)            xT, reused as y_pc
  //   [8388608, 33554432)     qkv: q_pd | k_pd | v_cp (8388608 each)
  //   [33554432, 34340864)    wq bf16 (786432)
  //   [34340864, 34603008)    wo bf16 (262144)
  unsigned short* xT   = ws;
  unsigned short* qkv  = ws + 8388608;
  unsigned short* y_pc = ws;
  unsigned short* wq   = ws + 33554432;
  unsigned short* wo   = wq + 786432;

  cvt_bf16<<<3072, 256, 0, stream>>>(qkv_w, wq, 786432);
  cvt_bf16<<<1024, 256, 0, stream>>>(out_w, wo, 262144);

  transpose_cvt<<<dim3(32, 16, 16), 256, 0, stream>>>(x, xT);

  gemm_qkv<<<dim3(12, 8, 16), 256, 0, stream>>>(xT, wq, qkv, qkv_b);

  attn_kernel<<<dim3(16, 128), 256, 0, stream>>>(
      qkv, qkv + 8388608, qkv + 16777216, y_pc);

  gemm_out<<<dim3(4, 8, 16), 256, 0, stream>>>(
      y_pc, wo, out, out_b, x, de);
}

// Round 7
// 293.190 us; speedup vs baseline: 1.3465x; 1.3465x over previous
//
#include <hip/hip_runtime.h>

typedef short bf16x8 __attribute__((ext_vector_type(8)));
typedef float f32x4 __attribute__((ext_vector_type(4)));

#define MFMA16(a,b,c) __builtin_amdgcn_mfma_f32_16x16x32_bf16((a),(b),(c),0,0,0)

static __device__ __forceinline__ unsigned short f2bf(float f){
  unsigned u; __builtin_memcpy(&u, &f, 4);
  u += 0x7fffu + ((u >> 16) & 1u);
  return (unsigned short)(u >> 16);
}
static __device__ __forceinline__ unsigned f32u(float f){
  unsigned u; __builtin_memcpy(&u, &f, 4); return u;
}

// ---------------------------------------------------------------------------
// Stage f32 tensor -> bf16.
// ---------------------------------------------------------------------------
__global__ __launch_bounds__(256) void cvt_bf16(
    const float* __restrict__ in, unsigned short* __restrict__ out, int n) {
  int i = blockIdx.x * 256 + threadIdx.x;
  if (i < n) out[i] = f2bf(in[i]);
}

// ---------------------------------------------------------------------------
// T0: x [n][512 c][1024 p] f32 -> xT [n][1024 p][512 c] bf16
// ---------------------------------------------------------------------------
__global__ __launch_bounds__(256) void transpose_cvt(
    const float* __restrict__ in, unsigned short* __restrict__ out)
{
  __shared__ unsigned short tile[32][33];
  const long base = (long)blockIdx.z * 512 * 1024;
  const int t = threadIdx.x, tx = t & 31, ty = t >> 5;
  const int c0 = blockIdx.x * 32, r0 = blockIdx.y * 32;
  const float* ib = in + base;
#pragma unroll
  for (int i = 0; i < 4; ++i)
    tile[ty + i * 8][tx] = f2bf(ib[(long)(r0 + ty + i * 8) * 1024 + c0 + tx]);
  __syncthreads();
  unsigned short* ob = out + base;
#pragma unroll
  for (int i = 0; i < 4; ++i)
    ob[(long)(c0 + ty + i * 8) * 512 + r0 + tx] = tile[tx][ty + i * 8];
}

// ---------------------------------------------------------------------------
// K1: QKV GEMM.  A = xT [n][1024 p][512 c] bf16, B = wq [1536 o][512 c] bf16,
// bias f32. Epilogue routes by o:
//   o in [0,512)    -> q_pd [n][h][p][64]  (qkv + 0)  PRE-SCALED by 0.125*log2e
//   o in [512,1024) -> k_pd [n][h][p][64]  (qkv + 8388608)
//   o in [1024,1536)-> v_cp [n][o-1024][p] (qkv + 16777216)
// ---------------------------------------------------------------------------
__global__ __launch_bounds__(256) void gemm_qkv(
    const unsigned short* __restrict__ A, const unsigned short* __restrict__ B,
    unsigned short* __restrict__ qkvout, const float* __restrict__ bias)
{
  const int M = 1024, K = 512;
  __shared__ unsigned short As[128 * 72];
  __shared__ unsigned short Bs[128 * 72];
  const int t = threadIdx.x, lane = t & 63, wv = t >> 6;
  const int quad = lane >> 4, ln = lane & 15;
  const int m0 = blockIdx.y * 128, n0 = blockIdx.x * 128;
  const long zb = blockIdx.z;
  A += zb * (long)M * K;

  f32x4 zero = {0.f, 0.f, 0.f, 0.f};
  f32x4 acc[4][4];
#pragma unroll
  for (int i = 0; i < 4; ++i)
#pragma unroll
    for (int j = 0; j < 4; ++j) acc[i][j] = zero;

  const int wm = (wv & 1) * 64, wn = (wv >> 1) * 64;

  for (int kt = 0; kt < K; kt += 64) {
#pragma unroll
    for (int i = 0; i < 4; ++i) {
      int chunk = t + 256 * i;
      int row = chunk >> 3, col = (chunk & 7) * 8;
      *(uint4*)&As[row * 72 + col] = *(const uint4*)&A[(long)(m0 + row) * K + kt + col];
      *(uint4*)&Bs[row * 72 + col] = *(const uint4*)&B[(long)(n0 + row) * K + kt + col];
    }
    __syncthreads();
#pragma unroll
    for (int kk = 0; kk < 64; kk += 32) {
      bf16x8 a[4], b[4];
#pragma unroll
      for (int i = 0; i < 4; ++i)
        a[i] = *(const bf16x8*)&As[(wm + i * 16 + ln) * 72 + kk + quad * 8];
#pragma unroll
      for (int j = 0; j < 4; ++j)
        b[j] = *(const bf16x8*)&Bs[(wn + j * 16 + ln) * 72 + kk + quad * 8];
#pragma unroll
      for (int i = 0; i < 4; ++i)
#pragma unroll
        for (int j = 0; j < 4; ++j)
          acc[i][j] = MFMA16(a[i], b[j], acc[i][j]);
    }
    __syncthreads();
  }

#pragma unroll
  for (int j = 0; j < 4; ++j) {
    int o = n0 + wn + j * 16 + ln;
    float bb = bias[o];
    int part = o >> 9;          // 0=q, 1=k, 2=v
    int h = (o >> 6) & 7, d = o & 63;
    float qs = (part == 0) ? 0.18033688f : 1.0f;  // 0.125 * log2(e)
#pragma unroll
    for (int i = 0; i < 4; ++i) {
      int p = m0 + wm + i * 16 + quad * 4;
      f32x4 v = acc[i][j];
      if (part < 2) {
        unsigned short* dst = qkvout + (long)part * 8388608
            + ((long)(zb * 8 + h) * 1024 + p) * 64 + d;
#pragma unroll
        for (int r = 0; r < 4; ++r) dst[r * 64] = f2bf((v[r] + bb) * qs);
      } else {
        long cidx = ((long)zb * 512 + (o - 1024)) * 1024 + p;
        ushort4 st;
        st.x = f2bf(v[0] + bb); st.y = f2bf(v[1] + bb);
        st.z = f2bf(v[2] + bb); st.w = f2bf(v[3] + bb);
        *(ushort4*)&qkvout[16777216 + cidx] = st;
      }
    }
  }
}

// ---------------------------------------------------------------------------
// K3: OUT GEMM + bias + dropout-scale + residual; f32 output.
// ---------------------------------------------------------------------------
__global__ __launch_bounds__(256) void gemm_out(
    const unsigned short* __restrict__ A, const unsigned short* __restrict__ B,
    float* __restrict__ C, const float* __restrict__ bias,
    const float* __restrict__ xin, const int* __restrict__ de_ptr)
{
  const int M = 1024, K = 512;
  __shared__ unsigned short As[128 * 72];
  __shared__ unsigned short Bs[128 * 72];
  const int t = threadIdx.x, lane = t & 63, wv = t >> 6;
  const int quad = lane >> 4, ln = lane & 15;
  const int m0 = blockIdx.y * 128, n0 = blockIdx.x * 128;
  const long zb = blockIdx.z;
  A += zb * (long)M * K;
  C += zb * 512l * M;
  xin += zb * 512l * M;

  f32x4 zero = {0.f, 0.f, 0.f, 0.f};
  f32x4 acc[4][4];
#pragma unroll
  for (int i = 0; i < 4; ++i)
#pragma unroll
    for (int j = 0; j < 4; ++j) acc[i][j] = zero;

  const int wm = (wv & 1) * 64, wn = (wv >> 1) * 64;

  for (int kt = 0; kt < K; kt += 64) {
#pragma unroll
    for (int i = 0; i < 4; ++i) {
      int chunk = t + 256 * i;
      int row = chunk >> 3, col = (chunk & 7) * 8;
      *(uint4*)&As[row * 72 + col] = *(const uint4*)&A[(long)(m0 + row) * K + kt + col];
      *(uint4*)&Bs[row * 72 + col] = *(const uint4*)&B[(long)(n0 + row) * K + kt + col];
    }
    __syncthreads();
#pragma unroll
    for (int kk = 0; kk < 64; kk += 32) {
      bf16x8 a[4], b[4];
#pragma unroll
      for (int i = 0; i < 4; ++i)
        a[i] = *(const bf16x8*)&As[(wm + i * 16 + ln) * 72 + kk + quad * 8];
#pragma unroll
      for (int j = 0; j < 4; ++j)
        b[j] = *(const bf16x8*)&Bs[(wn + j * 16 + ln) * 72 + kk + quad * 8];
#pragma unroll
      for (int i = 0; i < 4; ++i)
#pragma unroll
        for (int j = 0; j < 4; ++j)
          acc[i][j] = MFMA16(a[i], b[j], acc[i][j]);
    }
    __syncthreads();
  }

  float dscale = 1.0f / (1.0f - 0.1f * (float)de_ptr[0]);

#pragma unroll
  for (int j = 0; j < 4; ++j) {
    int o = n0 + wn + j * 16 + ln;
    float bb = bias[o];
#pragma unroll
    for (int i = 0; i < 4; ++i) {
      int p = m0 + wm + i * 16 + quad * 4;
      long cidx = (long)o * M + p;
      f32x4 v = acc[i][j];
      float4 rx = *(const float4*)&xin[cidx];
      float4 st;
      st.x = rx.x + (v[0] + bb) * dscale;
      st.y = rx.y + (v[1] + bb) * dscale;
      st.z = rx.z + (v[2] + bb) * dscale;
      st.w = rx.w + (v[3] + bb) * dscale;
      *(float4*)&C[cidx] = st;
    }
  }
}

// ---------------------------------------------------------------------------
// Flash attention v4: round-5 LDS structure + register prefetch + 2 Q-sets.
// grid (8 q-tiles of 128 rows, 128 (n,h)); 4 waves; wave handles q-rows
// {q0 + s*64 + wv*16 + ln} for s in {0,1}.
// q_pd (pre-scaled by 0.125*log2e), k_pd: [(n*8+h)*1024 + p][64]
// v_cp: [n][c'=h*64+d][1024 p];  out y_pc: [n][1024 p][512 c'] bf16.
//
// Per 128-key chunk: K/V tiles arrive via register prefetch (issued during
// the PREVIOUS chunk's compute; vmcnt drain lands at the LDS-write, one full
// compute-phase after issue). S^T = K Q^T per set; exp2 softmax (no max);
// P -> wave-private LDS -> B-frag; PV shares each Vs fragment across sets.
// ---------------------------------------------------------------------------
__global__ __launch_bounds__(256) void attn_kernel(
    const unsigned short* __restrict__ q_pd, const unsigned short* __restrict__ k_pd,
    const unsigned short* __restrict__ v_cp, unsigned short* __restrict__ y_pc)
{
  __shared__ unsigned short Ks[128 * 72];        // 18.4 KB
  __shared__ unsigned short Vs[64 * 136];        // 17.4 KB
  __shared__ unsigned short Ps[4 * 16 * 136];    // 17.4 KB, wave-private
  const int t = threadIdx.x, lane = t & 63, wv = t >> 6;
  const int quad = lane >> 4, ln = lane & 15;
  const int nh = blockIdx.y, n = nh >> 3, h = nh & 7;
  const int q0 = blockIdx.x * 128;

  // Q fragments for both sets (B-operand; n = ln, k = quad*8+j)
  bf16x8 qa[2][2];
#pragma unroll
  for (int s2 = 0; s2 < 2; ++s2) {
    const unsigned short* qb =
        q_pd + ((long)nh * 1024 + q0 + s2 * 64 + wv * 16 + ln) * 64;
    qa[s2][0] = *(const bf16x8*)(qb + quad * 8);
    qa[s2][1] = *(const bf16x8*)(qb + 32 + quad * 8);
  }

  f32x4 zero = {0.f, 0.f, 0.f, 0.f};
  float l_acc[2] = {0.f, 0.f};
  f32x4 o_acc[2][4];
#pragma unroll
  for (int s2 = 0; s2 < 2; ++s2)
#pragma unroll
    for (int nf = 0; nf < 4; ++nf) o_acc[s2][nf] = zero;

  const unsigned short* kg0 = k_pd + (long)nh * 1024 * 64;
  const unsigned short* vg0 = v_cp + ((long)n * 512 + h * 64) * 1024;
  unsigned short* Pw = &Ps[wv * 16 * 136];

  // coalesced staging coordinates (same as round 5)
  const int kr = t >> 3, kc = (t & 7) * 8;     // K: rows kr+32i, 8 shorts
  const int vr = t >> 4, vc = (t & 15) * 8;    // V: rows vr+16i, 8 shorts

  uint4 kreg[4], vreg[4];
#pragma unroll
  for (int i = 0; i < 4; ++i) {                // prefetch chunk 0
    kreg[i] = *(const uint4*)(kg0 + (long)(kr + 32 * i) * 64 + kc);
    vreg[i] = *(const uint4*)(vg0 + (long)(vr + 16 * i) * 1024 + vc);
  }

  for (int c = 0; c < 8; ++c) {
    __syncthreads();                           // prev compute done with Ks/Vs
#pragma unroll
    for (int i = 0; i < 4; ++i) {
      *(uint4*)&Ks[(kr + 32 * i) * 72 + kc]  = kreg[i];
      *(uint4*)&Vs[(vr + 16 * i) * 136 + vc] = vreg[i];
    }
    __syncthreads();

    if (c < 7) {                               // prefetch next chunk (in flight
      const unsigned short* kg = kg0 + (long)(c + 1) * 128 * 64;   // during
      const unsigned short* vg = vg0 + (c + 1) * 128;              // compute)
#pragma unroll
      for (int i = 0; i < 4; ++i) {
        kreg[i] = *(const uint4*)(kg + (long)(kr + 32 * i) * 64 + kc);
        vreg[i] = *(const uint4*)(vg + (long)(vr + 16 * i) * 1024 + vc);
      }
    }

    bf16x8 ap[2][4];
#pragma unroll
    for (int s2 = 0; s2 < 2; ++s2) {
      // ---- S^T = K Q^T : C row = key (j*16+quad*4+r), col = q (ln) ----
      f32x4 s[8];
#pragma unroll
      for (int j = 0; j < 8; ++j) {
        bf16x8 ka0 = *(const bf16x8*)&Ks[(j * 16 + ln) * 72 + quad * 8];
        bf16x8 ka1 = *(const bf16x8*)&Ks[(j * 16 + ln) * 72 + 32 + quad * 8];
        f32x4 sj = MFMA16(ka0, qa[s2][0], zero);
        s[j] = MFMA16(ka1, qa[s2][1], sj);
      }
      // ---- p = 2^s ----
      float ls = 0.f;
#pragma unroll
      for (int j = 0; j < 8; ++j)
#pragma unroll
        for (int r = 0; r < 4; ++r) {
          float pv = __builtin_amdgcn_exp2f(s[j][r]);
          s[j][r] = pv;
          ls += pv;
        }
      l_acc[s2] += ls;
      // ---- P -> wave-private LDS (packed b64), then B-frag reads ----
#pragma unroll
      for (int j = 0; j < 8; ++j) {
        uint2 pk;
        pk.x = __builtin_amdgcn_perm(f32u(s[j][1]), f32u(s[j][0]), 0x07060302u);
        pk.y = __builtin_amdgcn_perm(f32u(s[j][3]), f32u(s[j][2]), 0x07060302u);
        *(uint2*)&Pw[ln * 136 + j * 16 + quad * 4] = pk;
      }
#pragma unroll
      for (int k2 = 0; k2 < 4; ++k2)
        ap[s2][k2] = *(const bf16x8*)&Pw[ln * 136 + k2 * 32 + quad * 8];
    }

    // ---- O^T += V^T P^T : each Vs fragment feeds both sets ----
#pragma unroll
    for (int nf = 0; nf < 4; ++nf)
#pragma unroll
      for (int k2 = 0; k2 < 4; ++k2) {
        bf16x8 va = *(const bf16x8*)&Vs[(nf * 16 + ln) * 136 + k2 * 32 + quad * 8];
        o_acc[0][nf] = MFMA16(va, ap[0][k2], o_acc[0][nf]);
        o_acc[1][nf] = MFMA16(va, ap[1][k2], o_acc[1][nf]);
      }
  }

#pragma unroll
  for (int s2 = 0; s2 < 2; ++s2) {
    float la = l_acc[s2];
    la += __shfl_xor(la, 16);
    la += __shfl_xor(la, 32);
    float linv = 1.0f / la;
    const int p = q0 + s2 * 64 + wv * 16 + ln;
    unsigned short* yb = y_pc + ((long)n * 1024 + p) * 512 + h * 64 + quad * 4;
#pragma unroll
    for (int nf = 0; nf < 4; ++nf) {
      ushort4 st;
      st.x = f2bf(o_acc[s2][nf][0] * linv);
      st.y = f2bf(o_acc[s2][nf][1] * linv);
      st.z = f2bf(o_acc[s2][nf][2] * linv);
      st.w = f2bf(o_acc[s2][nf][3] * linv);
      *(ushort4*)&yb[nf * 16] = st;
    }
  }
}

// ---------------------------------------------------------------------------
extern "C" void kernel_launch(void* const* d_in, const int* in_sizes, int n_in,
                              void* d_out, int out_size, void* d_ws, size_t ws_size,
                              hipStream_t stream) {
  (void)in_sizes; (void)n_in; (void)out_size; (void)ws_size;
  const float* x     = (const float*)d_in[0];
  const float* qkv_w = (const float*)d_in[1];
  const float* qkv_b = (const float*)d_in[2];
  const float* out_w = (const float*)d_in[3];
  const float* out_b = (const float*)d_in[4];
  const int* de = (const int*)d_in[5];
  float* out = (float*)d_out;
  unsigned short* ws = (unsigned short*)d_ws;

  // ws layout (shorts), ~66 MiB total:
  //   [0, 8388608)            xT, reused as y_pc
  //   [8388608, 33554432)     qkv: q_pd | k_pd | v_cp (8388608 each)
  //   [33554432, 34340864)    wq bf16 (786432)
  //   [34340864, 34603008)    wo bf16 (262144)
  unsigned short* xT   = ws;
  unsigned short* qkv  = ws + 8388608;
  unsigned short* y_pc = ws;
  unsigned short* wq   = ws + 33554432;
  unsigned short* wo   = wq + 786432;

  cvt_bf16<<<3072, 256, 0, stream>>>(qkv_w, wq, 786432);
  cvt_bf16<<<1024, 256, 0, stream>>>(out_w, wo, 262144);

  transpose_cvt<<<dim3(32, 16, 16), 256, 0, stream>>>(x, xT);

  gemm_qkv<<<dim3(12, 8, 16), 256, 0, stream>>>(xT, wq, qkv, qkv_b);

  attn_kernel<<<dim3(8, 128), 256, 0, stream>>>(
      qkv, qkv + 8388608, qkv + 16777216, y_pc);

  gemm_out<<<dim3(4, 8, 16), 256, 0, stream>>>(
      y_pc, wo, out, out_b, x, de);
}

// Round 8
// 267.633 us; speedup vs baseline: 1.4751x; 1.0955x over previous
//
#include <hip/hip_runtime.h>

typedef short bf16x8 __attribute__((ext_vector_type(8)));
typedef float f32x4 __attribute__((ext_vector_type(4)));

#define MFMA16(a,b,c) __builtin_amdgcn_mfma_f32_16x16x32_bf16((a),(b),(c),0,0,0)

static __device__ __forceinline__ unsigned short f2bf(float f){
  unsigned u; __builtin_memcpy(&u, &f, 4);
  u += 0x7fffu + ((u >> 16) & 1u);
  return (unsigned short)(u >> 16);
}
static __device__ __forceinline__ unsigned f32u(float f){
  unsigned u; __builtin_memcpy(&u, &f, 4); return u;
}

// async global->LDS DMA, 16 B per lane; LDS dest = wave-uniform base + lane*16
static __device__ __forceinline__ void gload_lds16(const void* g, void* l) {
  __builtin_amdgcn_global_load_lds(
      (__attribute__((address_space(1))) void*)g,
      (__attribute__((address_space(3))) void*)l, 16, 0, 0);
}

// ---------------------------------------------------------------------------
// Stage f32 tensor -> bf16.
// ---------------------------------------------------------------------------
__global__ __launch_bounds__(256) void cvt_bf16(
    const float* __restrict__ in, unsigned short* __restrict__ out, int n) {
  int i = blockIdx.x * 256 + threadIdx.x;
  if (i < n) out[i] = f2bf(in[i]);
}

// ---------------------------------------------------------------------------
// T0: x [n][512 c][1024 p] f32 -> xT [n][1024 p][512 c] bf16
// ---------------------------------------------------------------------------
__global__ __launch_bounds__(256) void transpose_cvt(
    const float* __restrict__ in, unsigned short* __restrict__ out)
{
  __shared__ unsigned short tile[32][33];
  const long base = (long)blockIdx.z * 512 * 1024;
  const int t = threadIdx.x, tx = t & 31, ty = t >> 5;
  const int c0 = blockIdx.x * 32, r0 = blockIdx.y * 32;
  const float* ib = in + base;
#pragma unroll
  for (int i = 0; i < 4; ++i)
    tile[ty + i * 8][tx] = f2bf(ib[(long)(r0 + ty + i * 8) * 1024 + c0 + tx]);
  __syncthreads();
  unsigned short* ob = out + base;
#pragma unroll
  for (int i = 0; i < 4; ++i)
    ob[(long)(c0 + ty + i * 8) * 512 + r0 + tx] = tile[tx][ty + i * 8];
}

// ---------------------------------------------------------------------------
// K1: QKV GEMM (m97-style global_load_lds staging, unpadded LDS tiles).
// A = xT [n][1024 p][512 c] bf16, B = wq [1536 o][512 c] bf16, bias f32.
// Epilogue routes by o:
//   o in [0,512)    -> q_pd [n][h][p][64]  (qkv + 0)  PRE-SCALED by 0.125*log2e
//   o in [512,1024) -> k_pd [n][h][p][64]  (qkv + 8388608)
//   o in [1024,1536)-> v_cp [n][o-1024][p] (qkv + 16777216)
// ---------------------------------------------------------------------------
__global__ __launch_bounds__(256, 3) void gemm_qkv(
    const unsigned short* __restrict__ A, const unsigned short* __restrict__ B,
    unsigned short* __restrict__ qkvout, const float* __restrict__ bias)
{
  const int M = 1024, K = 512;
  __shared__ unsigned short As[128 * 64];   // 16 KB, mirrors global tile
  __shared__ unsigned short Bs[128 * 64];
  const int t = threadIdx.x, lane = t & 63, wv = t >> 6;
  const int quad = lane >> 4, ln = lane & 15;
  const int m0 = blockIdx.y * 128, n0 = blockIdx.x * 128;
  const long zb = blockIdx.z;
  A += zb * (long)M * K;

  // staging: wave wv covers rows [wv*32, wv*32+32); issue i covers 8 rows;
  // lane l -> row l>>3, col (l&7)*8 (16 B) within the issue block.
  const int srow = wv * 32 + (lane >> 3), scol = (lane & 7) * 8;

  f32x4 zero = {0.f, 0.f, 0.f, 0.f};
  f32x4 acc[4][4];
#pragma unroll
  for (int i = 0; i < 4; ++i)
#pragma unroll
    for (int j = 0; j < 4; ++j) acc[i][j] = zero;

  const int wm = (wv & 1) * 64, wn = (wv >> 1) * 64;

  for (int kt = 0; kt < K; kt += 64) {
#pragma unroll
    for (int i = 0; i < 4; ++i) {
      gload_lds16(&A[(long)(m0 + srow + i * 8) * K + kt + scol],
                  &As[(wv * 32 + i * 8) * 64]);
      gload_lds16(&B[(long)(n0 + srow + i * 8) * K + kt + scol],
                  &Bs[(wv * 32 + i * 8) * 64]);
    }
    __syncthreads();   // drains vmcnt -> LDS data visible
#pragma unroll
    for (int kk = 0; kk < 64; kk += 32) {
      bf16x8 a[4], b[4];
#pragma unroll
      for (int i = 0; i < 4; ++i)
        a[i] = *(const bf16x8*)&As[(wm + i * 16 + ln) * 64 + kk + quad * 8];
#pragma unroll
      for (int j = 0; j < 4; ++j)
        b[j] = *(const bf16x8*)&Bs[(wn + j * 16 + ln) * 64 + kk + quad * 8];
#pragma unroll
      for (int i = 0; i < 4; ++i)
#pragma unroll
        for (int j = 0; j < 4; ++j)
          acc[i][j] = MFMA16(a[i], b[j], acc[i][j]);
    }
    __syncthreads();   // compute done before next overwrite
  }

#pragma unroll
  for (int j = 0; j < 4; ++j) {
    int o = n0 + wn + j * 16 + ln;
    float bb = bias[o];
    int part = o >> 9;          // 0=q, 1=k, 2=v
    int h = (o >> 6) & 7, d = o & 63;
    float qs = (part == 0) ? 0.18033688f : 1.0f;  // 0.125 * log2(e)
#pragma unroll
    for (int i = 0; i < 4; ++i) {
      int p = m0 + wm + i * 16 + quad * 4;
      f32x4 v = acc[i][j];
      if (part < 2) {
        unsigned short* dst = qkvout + (long)part * 8388608
            + ((long)(zb * 8 + h) * 1024 + p) * 64 + d;
#pragma unroll
        for (int r = 0; r < 4; ++r) dst[r * 64] = f2bf((v[r] + bb) * qs);
      } else {
        long cidx = ((long)zb * 512 + (o - 1024)) * 1024 + p;
        ushort4 st;
        st.x = f2bf(v[0] + bb); st.y = f2bf(v[1] + bb);
        st.z = f2bf(v[2] + bb); st.w = f2bf(v[3] + bb);
        *(ushort4*)&qkvout[16777216 + cidx] = st;
      }
    }
  }
}

// ---------------------------------------------------------------------------
// K3: OUT GEMM (same staging) + bias + dropout-scale + residual; f32 output.
// ---------------------------------------------------------------------------
__global__ __launch_bounds__(256, 3) void gemm_out(
    const unsigned short* __restrict__ A, const unsigned short* __restrict__ B,
    float* __restrict__ C, const float* __restrict__ bias,
    const float* __restrict__ xin, const int* __restrict__ de_ptr)
{
  const int M = 1024, K = 512;
  __shared__ unsigned short As[128 * 64];
  __shared__ unsigned short Bs[128 * 64];
  const int t = threadIdx.x, lane = t & 63, wv = t >> 6;
  const int quad = lane >> 4, ln = lane & 15;
  const int m0 = blockIdx.y * 128, n0 = blockIdx.x * 128;
  const long zb = blockIdx.z;
  A += zb * (long)M * K;
  C += zb * 512l * M;
  xin += zb * 512l * M;

  const int srow = wv * 32 + (lane >> 3), scol = (lane & 7) * 8;

  f32x4 zero = {0.f, 0.f, 0.f, 0.f};
  f32x4 acc[4][4];
#pragma unroll
  for (int i = 0; i < 4; ++i)
#pragma unroll
    for (int j = 0; j < 4; ++j) acc[i][j] = zero;

  const int wm = (wv & 1) * 64, wn = (wv >> 1) * 64;

  for (int kt = 0; kt < K; kt += 64) {
#pragma unroll
    for (int i = 0; i < 4; ++i) {
      gload_lds16(&A[(long)(m0 + srow + i * 8) * K + kt + scol],
                  &As[(wv * 32 + i * 8) * 64]);
      gload_lds16(&B[(long)(n0 + srow + i * 8) * K + kt + scol],
                  &Bs[(wv * 32 + i * 8) * 64]);
    }
    __syncthreads();
#pragma unroll
    for (int kk = 0; kk < 64; kk += 32) {
      bf16x8 a[4], b[4];
#pragma unroll
      for (int i = 0; i < 4; ++i)
        a[i] = *(const bf16x8*)&As[(wm + i * 16 + ln) * 64 + kk + quad * 8];
#pragma unroll
      for (int j = 0; j < 4; ++j)
        b[j] = *(const bf16x8*)&Bs[(wn + j * 16 + ln) * 64 + kk + quad * 8];
#pragma unroll
      for (int i = 0; i < 4; ++i)
#pragma unroll
        for (int j = 0; j < 4; ++j)
          acc[i][j] = MFMA16(a[i], b[j], acc[i][j]);
    }
    __syncthreads();
  }

  float dscale = 1.0f / (1.0f - 0.1f * (float)de_ptr[0]);

#pragma unroll
  for (int j = 0; j < 4; ++j) {
    int o = n0 + wn + j * 16 + ln;
    float bb = bias[o];
#pragma unroll
    for (int i = 0; i < 4; ++i) {
      int p = m0 + wm + i * 16 + quad * 4;
      long cidx = (long)o * M + p;
      f32x4 v = acc[i][j];
      float4 rx = *(const float4*)&xin[cidx];
      float4 st;
      st.x = rx.x + (v[0] + bb) * dscale;
      st.y = rx.y + (v[1] + bb) * dscale;
      st.z = rx.z + (v[2] + bb) * dscale;
      st.w = rx.w + (v[3] + bb) * dscale;
      *(float4*)&C[cidx] = st;
    }
  }
}

// ---------------------------------------------------------------------------
// Flash attention v4 + correct VGPR budget.
// LDS (53 KB) caps occupancy at 3 blocks/CU = 3 waves/EU, so declare
// __launch_bounds__(256,3): allocator gets ~170 VGPRs -> the register
// prefetch (kreg/vreg, 32 VGPRs live across compute) fits WITHOUT spilling
// (round 7: VGPR target 104 -> 260 MB scratch spill traffic per dispatch).
// ---------------------------------------------------------------------------
__global__ __launch_bounds__(256, 3) void attn_kernel(
    const unsigned short* __restrict__ q_pd, const unsigned short* __restrict__ k_pd,
    const unsigned short* __restrict__ v_cp, unsigned short* __restrict__ y_pc)
{
  __shared__ unsigned short Ks[128 * 72];        // 18.4 KB
  __shared__ unsigned short Vs[64 * 136];        // 17.4 KB
  __shared__ unsigned short Ps[4 * 16 * 136];    // 17.4 KB, wave-private
  const int t = threadIdx.x, lane = t & 63, wv = t >> 6;
  const int quad = lane >> 4, ln = lane & 15;
  const int nh = blockIdx.y, n = nh >> 3, h = nh & 7;
  const int q0 = blockIdx.x * 128;

  // Q fragments for both sets (B-operand; n = ln, k = quad*8+j)
  bf16x8 qa[2][2];
#pragma unroll
  for (int s2 = 0; s2 < 2; ++s2) {
    const unsigned short* qb =
        q_pd + ((long)nh * 1024 + q0 + s2 * 64 + wv * 16 + ln) * 64;
    qa[s2][0] = *(const bf16x8*)(qb + quad * 8);
    qa[s2][1] = *(const bf16x8*)(qb + 32 + quad * 8);
  }

  f32x4 zero = {0.f, 0.f, 0.f, 0.f};
  float l_acc[2] = {0.f, 0.f};
  f32x4 o_acc[2][4];
#pragma unroll
  for (int s2 = 0; s2 < 2; ++s2)
#pragma unroll
    for (int nf = 0; nf < 4; ++nf) o_acc[s2][nf] = zero;

  const unsigned short* kg0 = k_pd + (long)nh * 1024 * 64;
  const unsigned short* vg0 = v_cp + ((long)n * 512 + h * 64) * 1024;
  unsigned short* Pw = &Ps[wv * 16 * 136];

  const int kr = t >> 3, kc = (t & 7) * 8;     // K: rows kr+32i, 8 shorts
  const int vr = t >> 4, vc = (t & 15) * 8;    // V: rows vr+16i, 8 shorts

  uint4 kreg[4], vreg[4];
#pragma unroll
  for (int i = 0; i < 4; ++i) {                // prefetch chunk 0
    kreg[i] = *(const uint4*)(kg0 + (long)(kr + 32 * i) * 64 + kc);
    vreg[i] = *(const uint4*)(vg0 + (long)(vr + 16 * i) * 1024 + vc);
  }

  for (int c = 0; c < 8; ++c) {
    __syncthreads();                           // prev compute done with Ks/Vs
#pragma unroll
    for (int i = 0; i < 4; ++i) {
      *(uint4*)&Ks[(kr + 32 * i) * 72 + kc]  = kreg[i];
      *(uint4*)&Vs[(vr + 16 * i) * 136 + vc] = vreg[i];
    }
    __syncthreads();

    if (c < 7) {                               // prefetch next chunk
      const unsigned short* kg = kg0 + (long)(c + 1) * 128 * 64;
      const unsigned short* vg = vg0 + (c + 1) * 128;
#pragma unroll
      for (int i = 0; i < 4; ++i) {
        kreg[i] = *(const uint4*)(kg + (long)(kr + 32 * i) * 64 + kc);
        vreg[i] = *(const uint4*)(vg + (long)(vr + 16 * i) * 1024 + vc);
      }
    }

    bf16x8 ap[2][4];
#pragma unroll
    for (int s2 = 0; s2 < 2; ++s2) {
      // ---- S^T = K Q^T : C row = key (j*16+quad*4+r), col = q (ln) ----
      f32x4 s[8];
#pragma unroll
      for (int j = 0; j < 8; ++j) {
        bf16x8 ka0 = *(const bf16x8*)&Ks[(j * 16 + ln) * 72 + quad * 8];
        bf16x8 ka1 = *(const bf16x8*)&Ks[(j * 16 + ln) * 72 + 32 + quad * 8];
        f32x4 sj = MFMA16(ka0, qa[s2][0], zero);
        s[j] = MFMA16(ka1, qa[s2][1], sj);
      }
      // ---- p = 2^s ----
      float ls = 0.f;
#pragma unroll
      for (int j = 0; j < 8; ++j)
#pragma unroll
        for (int r = 0; r < 4; ++r) {
          float pv = __builtin_amdgcn_exp2f(s[j][r]);
          s[j][r] = pv;
          ls += pv;
        }
      l_acc[s2] += ls;
      // ---- P -> wave-private LDS (packed b64), then B-frag reads ----
#pragma unroll
      for (int j = 0; j < 8; ++j) {
        uint2 pk;
        pk.x = __builtin_amdgcn_perm(f32u(s[j][1]), f32u(s[j][0]), 0x07060302u);
        pk.y = __builtin_amdgcn_perm(f32u(s[j][3]), f32u(s[j][2]), 0x07060302u);
        *(uint2*)&Pw[ln * 136 + j * 16 + quad * 4] = pk;
      }
#pragma unroll
      for (int k2 = 0; k2 < 4; ++k2)
        ap[s2][k2] = *(const bf16x8*)&Pw[ln * 136 + k2 * 32 + quad * 8];
    }

    // ---- O^T += V^T P^T : each Vs fragment feeds both sets ----
#pragma unroll
    for (int nf = 0; nf < 4; ++nf)
#pragma unroll
      for (int k2 = 0; k2 < 4; ++k2) {
        bf16x8 va = *(const bf16x8*)&Vs[(nf * 16 + ln) * 136 + k2 * 32 + quad * 8];
        o_acc[0][nf] = MFMA16(va, ap[0][k2], o_acc[0][nf]);
        o_acc[1][nf] = MFMA16(va, ap[1][k2], o_acc[1][nf]);
      }
  }

#pragma unroll
  for (int s2 = 0; s2 < 2; ++s2) {
    float la = l_acc[s2];
    la += __shfl_xor(la, 16);
    la += __shfl_xor(la, 32);
    float linv = 1.0f / la;
    const int p = q0 + s2 * 64 + wv * 16 + ln;
    unsigned short* yb = y_pc + ((long)n * 1024 + p) * 512 + h * 64 + quad * 4;
#pragma unroll
    for (int nf = 0; nf < 4; ++nf) {
      ushort4 st;
      st.x = f2bf(o_acc[s2][nf][0] * linv);
      st.y = f2bf(o_acc[s2][nf][1] * linv);
      st.z = f2bf(o_acc[s2][nf][2] * linv);
      st.w = f2bf(o_acc[s2][nf][3] * linv);
      *(ushort4*)&yb[nf * 16] = st;
    }
  }
}

// ---------------------------------------------------------------------------
extern "C" void kernel_launch(void* const* d_in, const int* in_sizes, int n_in,
                              void* d_out, int out_size, void* d_ws, size_t ws_size,
                              hipStream_t stream) {
  (void)in_sizes; (void)n_in; (void)out_size; (void)ws_size;
  const float* x     = (const float*)d_in[0];
  const float* qkv_w = (const float*)d_in[1];
  const float* qkv_b = (const float*)d_in[2];
  const float* out_w = (const float*)d_in[3];
  const float* out_b = (const float*)d_in[4];
  const int* de = (const int*)d_in[5];
  float* out = (float*)d_out;
  unsigned short* ws = (unsigned short*)d_ws;

  // ws layout (shorts), ~66 MiB total:
  //   [0, 8388608)            xT, reused as y_pc
  //   [8388608, 33554432)     qkv: q_pd | k_pd | v_cp (8388608 each)
  //   [33554432, 34340864)    wq bf16 (786432)
  //   [34340864, 34603008)    wo bf16 (262144)
  unsigned short* xT   = ws;
  unsigned short* qkv  = ws + 8388608;
  unsigned short* y_pc = ws;
  unsigned short* wq   = ws + 33554432;
  unsigned short* wo   = wq + 786432;

  cvt_bf16<<<3072, 256, 0, stream>>>(qkv_w, wq, 786432);
  cvt_bf16<<<1024, 256, 0, stream>>>(out_w, wo, 262144);

  transpose_cvt<<<dim3(32, 16, 16), 256, 0, stream>>>(x, xT);

  gemm_qkv<<<dim3(12, 8, 16), 256, 0, stream>>>(xT, wq, qkv, qkv_b);

  attn_kernel<<<dim3(8, 128), 256, 0, stream>>>(
      qkv, qkv + 8388608, qkv + 16777216, y_pc);

  gemm_out<<<dim3(4, 8, 16), 256, 0, stream>>>(
      y_pc, wo, out, out_b, x, de);
}

// Round 9
// 236.169 us; speedup vs baseline: 1.6716x; 1.1332x over previous
//
#include <hip/hip_runtime.h>

typedef short bf16x8 __attribute__((ext_vector_type(8)));
typedef float f32x4 __attribute__((ext_vector_type(4)));

#define MFMA16(a,b,c) __builtin_amdgcn_mfma_f32_16x16x32_bf16((a),(b),(c),0,0,0)

static __device__ __forceinline__ unsigned short f2bf(float f){
  unsigned u; __builtin_memcpy(&u, &f, 4);
  u += 0x7fffu + ((u >> 16) & 1u);
  return (unsigned short)(u >> 16);
}
static __device__ __forceinline__ unsigned f32u(float f){
  unsigned u; __builtin_memcpy(&u, &f, 4); return u;
}

// async global->LDS DMA, 16 B per lane; LDS dest = wave-uniform base + lane*16
static __device__ __forceinline__ void gload_lds16(const void* g, void* l) {
  __builtin_amdgcn_global_load_lds(
      (__attribute__((address_space(1))) void*)g,
      (__attribute__((address_space(3))) void*)l, 16, 0, 0);
}

// ---------------------------------------------------------------------------
// Stage f32 tensor -> bf16.
// ---------------------------------------------------------------------------
__global__ __launch_bounds__(256) void cvt_bf16(
    const float* __restrict__ in, unsigned short* __restrict__ out, int n) {
  int i = blockIdx.x * 256 + threadIdx.x;
  if (i < n) out[i] = f2bf(in[i]);
}

// ---------------------------------------------------------------------------
// T0: x [n][512 c][1024 p] f32 -> xT [n][1024 p][512 c] bf16
// ---------------------------------------------------------------------------
__global__ __launch_bounds__(256) void transpose_cvt(
    const float* __restrict__ in, unsigned short* __restrict__ out)
{
  __shared__ unsigned short tile[32][33];
  const long base = (long)blockIdx.z * 512 * 1024;
  const int t = threadIdx.x, tx = t & 31, ty = t >> 5;
  const int c0 = blockIdx.x * 32, r0 = blockIdx.y * 32;
  const float* ib = in + base;
#pragma unroll
  for (int i = 0; i < 4; ++i)
    tile[ty + i * 8][tx] = f2bf(ib[(long)(r0 + ty + i * 8) * 1024 + c0 + tx]);
  __syncthreads();
  unsigned short* ob = out + base;
#pragma unroll
  for (int i = 0; i < 4; ++i)
    ob[(long)(c0 + ty + i * 8) * 512 + r0 + tx] = tile[tx][ty + i * 8];
}

// ---------------------------------------------------------------------------
// K1: QKV GEMM (global_load_lds staging, unpadded LDS tiles).
// A = xT [n][1024 p][512 c] bf16, B = wq [1536 o][512 c] bf16, bias f32.
// Epilogue routes by o:
//   o in [0,512)    -> q_pd [n][h][p][64]  (qkv + 0)  PRE-SCALED by 0.125*log2e
//   o in [512,1024) -> k_pd [n][h][p][64]  (qkv + 8388608)
//   o in [1024,1536)-> v_cp [n][o-1024][p] (qkv + 16777216)
// ---------------------------------------------------------------------------
__global__ __launch_bounds__(256, 3) void gemm_qkv(
    const unsigned short* __restrict__ A, const unsigned short* __restrict__ B,
    unsigned short* __restrict__ qkvout, const float* __restrict__ bias)
{
  const int M = 1024, K = 512;
  __shared__ unsigned short As[128 * 64];   // 16 KB, mirrors global tile
  __shared__ unsigned short Bs[128 * 64];
  const int t = threadIdx.x, lane = t & 63, wv = t >> 6;
  const int quad = lane >> 4, ln = lane & 15;
  const int m0 = blockIdx.y * 128, n0 = blockIdx.x * 128;
  const long zb = blockIdx.z;
  A += zb * (long)M * K;

  const int srow = wv * 32 + (lane >> 3), scol = (lane & 7) * 8;

  f32x4 zero = {0.f, 0.f, 0.f, 0.f};
  f32x4 acc[4][4];
#pragma unroll
  for (int i = 0; i < 4; ++i)
#pragma unroll
    for (int j = 0; j < 4; ++j) acc[i][j] = zero;

  const int wm = (wv & 1) * 64, wn = (wv >> 1) * 64;

  for (int kt = 0; kt < K; kt += 64) {
#pragma unroll
    for (int i = 0; i < 4; ++i) {
      gload_lds16(&A[(long)(m0 + srow + i * 8) * K + kt + scol],
                  &As[(wv * 32 + i * 8) * 64]);
      gload_lds16(&B[(long)(n0 + srow + i * 8) * K + kt + scol],
                  &Bs[(wv * 32 + i * 8) * 64]);
    }
    __syncthreads();   // drains vmcnt -> LDS data visible
#pragma unroll
    for (int kk = 0; kk < 64; kk += 32) {
      bf16x8 a[4], b[4];
#pragma unroll
      for (int i = 0; i < 4; ++i)
        a[i] = *(const bf16x8*)&As[(wm + i * 16 + ln) * 64 + kk + quad * 8];
#pragma unroll
      for (int j = 0; j < 4; ++j)
        b[j] = *(const bf16x8*)&Bs[(wn + j * 16 + ln) * 64 + kk + quad * 8];
#pragma unroll
      for (int i = 0; i < 4; ++i)
#pragma unroll
        for (int j = 0; j < 4; ++j)
          acc[i][j] = MFMA16(a[i], b[j], acc[i][j]);
    }
    __syncthreads();   // compute done before next overwrite
  }

#pragma unroll
  for (int j = 0; j < 4; ++j) {
    int o = n0 + wn + j * 16 + ln;
    float bb = bias[o];
    int part = o >> 9;          // 0=q, 1=k, 2=v
    int h = (o >> 6) & 7, d = o & 63;
    float qs = (part == 0) ? 0.18033688f : 1.0f;  // 0.125 * log2(e)
#pragma unroll
    for (int i = 0; i < 4; ++i) {
      int p = m0 + wm + i * 16 + quad * 4;
      f32x4 v = acc[i][j];
      if (part < 2) {
        unsigned short* dst = qkvout + (long)part * 8388608
            + ((long)(zb * 8 + h) * 1024 + p) * 64 + d;
#pragma unroll
        for (int r = 0; r < 4; ++r) dst[r * 64] = f2bf((v[r] + bb) * qs);
      } else {
        long cidx = ((long)zb * 512 + (o - 1024)) * 1024 + p;
        ushort4 st;
        st.x = f2bf(v[0] + bb); st.y = f2bf(v[1] + bb);
        st.z = f2bf(v[2] + bb); st.w = f2bf(v[3] + bb);
        *(ushort4*)&qkvout[16777216 + cidx] = st;
      }
    }
  }
}

// ---------------------------------------------------------------------------
// K3: OUT GEMM (same staging) + bias + dropout-scale + residual; f32 output.
// ---------------------------------------------------------------------------
__global__ __launch_bounds__(256, 3) void gemm_out(
    const unsigned short* __restrict__ A, const unsigned short* __restrict__ B,
    float* __restrict__ C, const float* __restrict__ bias,
    const float* __restrict__ xin, const int* __restrict__ de_ptr)
{
  const int M = 1024, K = 512;
  __shared__ unsigned short As[128 * 64];
  __shared__ unsigned short Bs[128 * 64];
  const int t = threadIdx.x, lane = t & 63, wv = t >> 6;
  const int quad = lane >> 4, ln = lane & 15;
  const int m0 = blockIdx.y * 128, n0 = blockIdx.x * 128;
  const long zb = blockIdx.z;
  A += zb * (long)M * K;
  C += zb * 512l * M;
  xin += zb * 512l * M;

  const int srow = wv * 32 + (lane >> 3), scol = (lane & 7) * 8;

  f32x4 zero = {0.f, 0.f, 0.f, 0.f};
  f32x4 acc[4][4];
#pragma unroll
  for (int i = 0; i < 4; ++i)
#pragma unroll
    for (int j = 0; j < 4; ++j) acc[i][j] = zero;

  const int wm = (wv & 1) * 64, wn = (wv >> 1) * 64;

  for (int kt = 0; kt < K; kt += 64) {
#pragma unroll
    for (int i = 0; i < 4; ++i) {
      gload_lds16(&A[(long)(m0 + srow + i * 8) * K + kt + scol],
                  &As[(wv * 32 + i * 8) * 64]);
      gload_lds16(&B[(long)(n0 + srow + i * 8) * K + kt + scol],
                  &Bs[(wv * 32 + i * 8) * 64]);
    }
    __syncthreads();
#pragma unroll
    for (int kk = 0; kk < 64; kk += 32) {
      bf16x8 a[4], b[4];
#pragma unroll
      for (int i = 0; i < 4; ++i)
        a[i] = *(const bf16x8*)&As[(wm + i * 16 + ln) * 64 + kk + quad * 8];
#pragma unroll
      for (int j = 0; j < 4; ++j)
        b[j] = *(const bf16x8*)&Bs[(wn + j * 16 + ln) * 64 + kk + quad * 8];
#pragma unroll
      for (int i = 0; i < 4; ++i)
#pragma unroll
        for (int j = 0; j < 4; ++j)
          acc[i][j] = MFMA16(a[i], b[j], acc[i][j]);
    }
    __syncthreads();
  }

  float dscale = 1.0f / (1.0f - 0.1f * (float)de_ptr[0]);

#pragma unroll
  for (int j = 0; j < 4; ++j) {
    int o = n0 + wn + j * 16 + ln;
    float bb = bias[o];
#pragma unroll
    for (int i = 0; i < 4; ++i) {
      int p = m0 + wm + i * 16 + quad * 4;
      long cidx = (long)o * M + p;
      f32x4 v = acc[i][j];
      float4 rx = *(const float4*)&xin[cidx];
      float4 st;
      st.x = rx.x + (v[0] + bb) * dscale;
      st.y = rx.y + (v[1] + bb) * dscale;
      st.z = rx.z + (v[2] + bb) * dscale;
      st.w = rx.w + (v[3] + bb) * dscale;
      *(float4*)&C[cidx] = st;
    }
  }
}

// ---------------------------------------------------------------------------
// Flash attention v5: K/V staging via global_load_lds (ZERO register
// footprint -> nothing to spill; rounds 7/8's uint4 prefetch caused ~260 MB
// scratch writes per dispatch). Unpadded DMA-dest tiles (m97 pattern):
// Ks[128x64], Vs[64x128]; Ps stays padded (regular ds_write).
// grid (8 q-tiles of 128 rows, 128 (n,h)); 4 waves; 2 Q-sets per wave.
// ---------------------------------------------------------------------------
__global__ __launch_bounds__(256, 3) void attn_kernel(
    const unsigned short* __restrict__ q_pd, const unsigned short* __restrict__ k_pd,
    const unsigned short* __restrict__ v_cp, unsigned short* __restrict__ y_pc)
{
  __shared__ unsigned short Ks[128 * 64];        // 16 KB, DMA dest
  __shared__ unsigned short Vs[64 * 128];        // 16 KB, DMA dest
  __shared__ unsigned short Ps[4 * 16 * 136];    // 17.4 KB, wave-private
  const int t = threadIdx.x, lane = t & 63, wv = t >> 6;
  const int quad = lane >> 4, ln = lane & 15;
  const int nh = blockIdx.y, n = nh >> 3, h = nh & 7;
  const int q0 = blockIdx.x * 128;

  // Q fragments for both sets (B-operand; n = ln, k = quad*8+j)
  bf16x8 qa[2][2];
#pragma unroll
  for (int s2 = 0; s2 < 2; ++s2) {
    const unsigned short* qb =
        q_pd + ((long)nh * 1024 + q0 + s2 * 64 + wv * 16 + ln) * 64;
    qa[s2][0] = *(const bf16x8*)(qb + quad * 8);
    qa[s2][1] = *(const bf16x8*)(qb + 32 + quad * 8);
  }

  f32x4 zero = {0.f, 0.f, 0.f, 0.f};
  float l_acc[2] = {0.f, 0.f};
  f32x4 o_acc[2][4];
#pragma unroll
  for (int s2 = 0; s2 < 2; ++s2)
#pragma unroll
    for (int nf = 0; nf < 4; ++nf) o_acc[s2][nf] = zero;

  const unsigned short* kg0 = k_pd + (long)nh * 1024 * 64;
  const unsigned short* vg0 = v_cp + ((long)n * 512 + h * 64) * 1024;
  unsigned short* Pw = &Ps[wv * 16 * 136];

  // DMA staging coords: K wave-rows [wv*32,+32), 4 issues x 8 rows;
  //                     V wave-rows [wv*16,+16), 4 issues x 4 rows.
  const int krow = lane >> 3, kcol = (lane & 7) * 8;
  const int vrow = lane >> 4, vcol = (lane & 15) * 8;

  for (int c = 0; c < 8; ++c) {
    const unsigned short* kg = kg0 + (long)c * 128 * 64;
    const unsigned short* vg = vg0 + c * 128;
#pragma unroll
    for (int i = 0; i < 4; ++i) {
      gload_lds16(kg + (long)(wv * 32 + i * 8 + krow) * 64 + kcol,
                  &Ks[(wv * 32 + i * 8) * 64]);
      gload_lds16(vg + (long)(wv * 16 + i * 4 + vrow) * 1024 + vcol,
                  &Vs[(wv * 16 + i * 4) * 128]);
    }
    __syncthreads();   // drains vmcnt -> DMA data visible

    bf16x8 ap[2][4];
#pragma unroll
    for (int s2 = 0; s2 < 2; ++s2) {
      // ---- S^T = K Q^T : C row = key (j*16+quad*4+r), col = q (ln) ----
      f32x4 s[8];
#pragma unroll
      for (int j = 0; j < 8; ++j) {
        bf16x8 ka0 = *(const bf16x8*)&Ks[(j * 16 + ln) * 64 + quad * 8];
        bf16x8 ka1 = *(const bf16x8*)&Ks[(j * 16 + ln) * 64 + 32 + quad * 8];
        f32x4 sj = MFMA16(ka0, qa[s2][0], zero);
        s[j] = MFMA16(ka1, qa[s2][1], sj);
      }
      // ---- p = 2^s (logits pre-scaled by 0.125*log2e) ----
      float ls = 0.f;
#pragma unroll
      for (int j = 0; j < 8; ++j)
#pragma unroll
        for (int r = 0; r < 4; ++r) {
          float pv = __builtin_amdgcn_exp2f(s[j][r]);
          s[j][r] = pv;
          ls += pv;
        }
      l_acc[s2] += ls;
      // ---- P -> wave-private LDS (packed b64), then B-frag reads ----
#pragma unroll
      for (int j = 0; j < 8; ++j) {
        uint2 pk;
        pk.x = __builtin_amdgcn_perm(f32u(s[j][1]), f32u(s[j][0]), 0x07060302u);
        pk.y = __builtin_amdgcn_perm(f32u(s[j][3]), f32u(s[j][2]), 0x07060302u);
        *(uint2*)&Pw[ln * 136 + j * 16 + quad * 4] = pk;
      }
#pragma unroll
      for (int k2 = 0; k2 < 4; ++k2)
        ap[s2][k2] = *(const bf16x8*)&Pw[ln * 136 + k2 * 32 + quad * 8];
    }

    // ---- O^T += V^T P^T : each Vs fragment feeds both sets ----
#pragma unroll
    for (int nf = 0; nf < 4; ++nf)
#pragma unroll
      for (int k2 = 0; k2 < 4; ++k2) {
        bf16x8 va = *(const bf16x8*)&Vs[(nf * 16 + ln) * 128 + k2 * 32 + quad * 8];
        o_acc[0][nf] = MFMA16(va, ap[0][k2], o_acc[0][nf]);
        o_acc[1][nf] = MFMA16(va, ap[1][k2], o_acc[1][nf]);
      }
    __syncthreads();   // compute done before next chunk's DMA overwrite
  }

#pragma unroll
  for (int s2 = 0; s2 < 2; ++s2) {
    float la = l_acc[s2];
    la += __shfl_xor(la, 16);
    la += __shfl_xor(la, 32);
    float linv = 1.0f / la;
    const int p = q0 + s2 * 64 + wv * 16 + ln;
    unsigned short* yb = y_pc + ((long)n * 1024 + p) * 512 + h * 64 + quad * 4;
#pragma unroll
    for (int nf = 0; nf < 4; ++nf) {
      ushort4 st;
      st.x = f2bf(o_acc[s2][nf][0] * linv);
      st.y = f2bf(o_acc[s2][nf][1] * linv);
      st.z = f2bf(o_acc[s2][nf][2] * linv);
      st.w = f2bf(o_acc[s2][nf][3] * linv);
      *(ushort4*)&yb[nf * 16] = st;
    }
  }
}

// ---------------------------------------------------------------------------
extern "C" void kernel_launch(void* const* d_in, const int* in_sizes, int n_in,
                              void* d_out, int out_size, void* d_ws, size_t ws_size,
                              hipStream_t stream) {
  (void)in_sizes; (void)n_in; (void)out_size; (void)ws_size;
  const float* x     = (const float*)d_in[0];
  const float* qkv_w = (const float*)d_in[1];
  const float* qkv_b = (const float*)d_in[2];
  const float* out_w = (const float*)d_in[3];
  const float* out_b = (const float*)d_in[4];
  const int* de = (const int*)d_in[5];
  float* out = (float*)d_out;
  unsigned short* ws = (unsigned short*)d_ws;

  // ws layout (shorts), ~66 MiB total:
  //   [0, 8388608)            xT, reused as y_pc
  //   [8388608, 33554432)     qkv: q_pd | k_pd | v_cp (8388608 each)
  //   [33554432, 34340864)    wq bf16 (786432)
  //   [34340864, 34603008)    wo bf16 (262144)
  unsigned short* xT   = ws;
  unsigned short* qkv  = ws + 8388608;
  unsigned short* y_pc = ws;
  unsigned short* wq   = ws + 33554432;
  unsigned short* wo   = wq + 786432;

  cvt_bf16<<<3072, 256, 0, stream>>>(qkv_w, wq, 786432);
  cvt_bf16<<<1024, 256, 0, stream>>>(out_w, wo, 262144);

  transpose_cvt<<<dim3(32, 16, 16), 256, 0, stream>>>(x, xT);

  gemm_qkv<<<dim3(12, 8, 16), 256, 0, stream>>>(xT, wq, qkv, qkv_b);

  attn_kernel<<<dim3(8, 128), 256, 0, stream>>>(
      qkv, qkv + 8388608, qkv + 16777216, y_pc);

  gemm_out<<<dim3(4, 8, 16), 256, 0, stream>>>(
      y_pc, wo, out, out_b, x, de);
}